// Round 2
// baseline (152.233 us; speedup 1.0000x reference)
//
#include <hip/hip_runtime.h>
#include <math.h>

// CapLayer, fully fused. Routing degeneracy (b=0 init -> softmax uniform ->
// o-independent v -> b stays o-constant): output = broadcast over o of
// squash(colsum(pred)/64), colsum[b,d] = sum_s sum_i W[s,d,i]*U[b,s,i],
// U[b,s,i] = sum_{p<256} x[b, s*8192 + p*32 + i].
//
// Single kernel: 2048 blocks, one per (b,s) 32KB chunk. Each block:
//   A) reduce 256x32 chunk -> U[32] (LDS tree)
//   B) contract with W[s] (8KB) -> partial[64], atomicAdd into acc[b*64+d]
//   C) completion counter per b; the 32nd block for b squashes and writes
//      the 64KB broadcast output slice. Cross-XCD coherence: device-scope
//      atomics for writes, agent-scope atomic loads for the final read.

__global__ __launch_bounds__(256) void k_caplayer(const float* __restrict__ x,
                                                  const float* __restrict__ W,
                                                  float* __restrict__ out,
                                                  float* __restrict__ acc,
                                                  int* __restrict__ cnt) {
    const int blk = blockIdx.x;          // b*32 + s
    const int b   = blk >> 5;
    const int s   = blk & 31;
    const int t   = threadIdx.x;

    // ---- Phase A: reduce this (b,s) chunk over p -> U[32] ----
    const float* xb = x + (size_t)blk * 8192;
    const int i4 = t & 7;                // which float4 of the 32-float row
    const int pl = t >> 3;               // p-lane 0..31
    float4 a = make_float4(0.f, 0.f, 0.f, 0.f);
#pragma unroll
    for (int k = 0; k < 8; ++k) {
        const float4 v = *reinterpret_cast<const float4*>(
            xb + (size_t)(pl + 32 * k) * 32 + i4 * 4);
        a.x += v.x; a.y += v.y; a.z += v.z; a.w += v.w;
    }
    __shared__ float4 red4[256];
    red4[t] = a;
    __syncthreads();
#pragma unroll
    for (int st = 128; st >= 8; st >>= 1) {
        if (t < st) {
            const float4 o = red4[t + st];
            red4[t].x += o.x; red4[t].y += o.y; red4[t].z += o.z; red4[t].w += o.w;
        }
        __syncthreads();
    }
    __shared__ float Uf[32];
    if (t < 8) *reinterpret_cast<float4*>(Uf + 4 * t) = red4[t];
    __syncthreads();

    // ---- Phase B: partial[d] = sum_i W[s,d,i] * U[i], atomic into acc ----
    const int d = t & 63;
    const int q = t >> 6;                // i-quarter 0..3
    const float4* W4 = reinterpret_cast<const float4*>(W) + ((size_t)s * 512 + d * 8 + q * 2);
    const float4* U4 = reinterpret_cast<const float4*>(Uf) + q * 2;
    const float4 w0 = W4[0], w1 = W4[1];
    const float4 u0 = U4[0], u1 = U4[1];
    const float part = w0.x * u0.x + w0.y * u0.y + w0.z * u0.z + w0.w * u0.w
                     + w1.x * u1.x + w1.y * u1.y + w1.z * u1.z + w1.w * u1.w;
    __shared__ float pb[256];
    pb[t] = part;
    __syncthreads();
    if (t < 64) {
        const float tot = pb[t] + pb[t + 64] + pb[t + 128] + pb[t + 192];
        atomicAdd(&acc[b * 64 + t], tot);   // device-scope by default
    }
    __syncthreads();                        // drains vmcnt: atomics performed

    // ---- Phase C: last block per b finishes ----
    __shared__ int lastflag;
    if (t == 0) {
        __threadfence();
        const int old = atomicAdd(&cnt[b], 1);
        lastflag = (old == 31);
    }
    __syncthreads();
    if (lastflag) {
        __shared__ float vsh[64];
        if (t < 64) {
            const float sv = __hip_atomic_load(&acc[b * 64 + t],
                                               __ATOMIC_RELAXED,
                                               __HIP_MEMORY_SCOPE_AGENT);
            const float s1 = sv * (1.0f / 64.0f);
            float sq = s1 * s1;
#pragma unroll
            for (int off = 32; off >= 1; off >>= 1) sq += __shfl_xor(sq, off, 64);
            const float coeff = sqrtf(sq) / (1.0f + sq);  // n^2/(1+n^2)/n
            vsh[t] = s1 * coeff;
        }
        __syncthreads();
        float* ob = out + (size_t)b * 4096;
        const float val = vsh[t & 63];
#pragma unroll
        for (int qq = 0; qq < 16; ++qq) ob[t + 256 * qq] = val;
    }
}

extern "C" void kernel_launch(void* const* d_in, const int* in_sizes, int n_in,
                              void* d_out, int out_size, void* d_ws, size_t ws_size,
                              hipStream_t stream) {
    const float* x = (const float*)d_in[0];   // [64, 1024, 16, 16] fp32
    const float* W = (const float*)d_in[1];   // [32, 64, 32] fp32
    float* out = (float*)d_out;               // [64, 64, 64] fp32
    float* acc = (float*)d_ws;                // [64*64] fp32
    int*   cnt = (int*)((char*)d_ws + 64 * 64 * sizeof(float));  // [64]

    hipMemsetAsync(d_ws, 0, 64 * 64 * sizeof(float) + 64 * sizeof(int), stream);
    k_caplayer<<<2048, 256, 0, stream>>>(x, W, out, acc, cnt);
}

// Round 3
// 101.629 us; speedup vs baseline: 1.4979x; 1.4979x over previous
//
#include <hip/hip_runtime.h>
#include <math.h>

// CapLayer, fused, fence-free. Routing degeneracy (b=0 -> softmax uniform ->
// o-independent v -> b stays o-constant over all 3 iters): output =
// broadcast_o( squash( colsum(pred)/64 ) ),
//   colsum[b,d] = sum_s sum_i W[s,d,i] * U[b,s,i]
//   U[b,s,i]    = sum_{p<256} x[b, s*8192 + p*32 + i]   (row-major reinterp)
//
// One kernel, 2048 blocks (one per (b,s) 32KB chunk):
//   A) stream-reduce chunk -> U[32]   (3 shuffles + 1 barrier)
//   B) contract with W[s] -> 64 partials, agent-scope atomicAdd into acc
//   C) per-b completion counter; 32nd block squashes + writes 16KB output.
// Cross-XCD protocol WITHOUT L2-writeback fences: data writes are agent
// atomics (coherence-point execution); wave-0 orders its acc atomics before
// the cnt RMW with a plain s_waitcnt vmcnt(0). R2's __threadfence() (2048x
// agent release -> L2 writeback storm) was the 100us pathology.

__global__ __launch_bounds__(256) void k_caplayer(const float* __restrict__ x,
                                                  const float* __restrict__ W,
                                                  float* __restrict__ out,
                                                  float* __restrict__ acc,
                                                  int* __restrict__ cnt) {
    const int blk = blockIdx.x;          // b*32 + s
    const int b   = blk >> 5;
    const int s   = blk & 31;
    const int t   = threadIdx.x;
    const int wv  = t >> 6;              // wave 0..3
    const int ln  = t & 63;

    // ---- Phase A: reduce 256 rows x 32 cols -> U[32] ----
    const float* xb = x + (size_t)blk * 8192;
    float4 a = make_float4(0.f, 0.f, 0.f, 0.f);
#pragma unroll
    for (int k = 0; k < 8; ++k) {        // float4 idx t+256k: i4 = t&7 const
        const float4 v = *reinterpret_cast<const float4*>(xb + (size_t)(t + 256 * k) * 4);
        a.x += v.x; a.y += v.y; a.z += v.z; a.w += v.w;
    }
#pragma unroll
    for (int off = 8; off <= 32; off <<= 1) {   // lanes sharing t&7 = same i4
        a.x += __shfl_xor(a.x, off, 64);
        a.y += __shfl_xor(a.y, off, 64);
        a.z += __shfl_xor(a.z, off, 64);
        a.w += __shfl_xor(a.w, off, 64);
    }
    __shared__ float4 wsum[4][8];
    if (ln < 8) wsum[wv][ln] = a;
    __syncthreads();
    __shared__ float Uf[32];
    if (t < 8) {
        const float4 r0 = wsum[0][t], r1 = wsum[1][t], r2 = wsum[2][t], r3 = wsum[3][t];
        float4 u;
        u.x = r0.x + r1.x + r2.x + r3.x;
        u.y = r0.y + r1.y + r2.y + r3.y;
        u.z = r0.z + r1.z + r2.z + r3.z;
        u.w = r0.w + r1.w + r2.w + r3.w;
        *reinterpret_cast<float4*>(Uf + 4 * t) = u;
    }
    __syncthreads();

    // ---- Phase B: partial[d] = sum_i W[s,d,i]*U[i]; atomic into acc ----
    const int d = t & 63;
    const int q = t >> 6;                // i-quarter
    const float4* W4 = reinterpret_cast<const float4*>(W) + ((size_t)s * 512 + d * 8 + q * 2);
    const float4* U4 = reinterpret_cast<const float4*>(Uf) + q * 2;
    const float4 w0 = W4[0], w1 = W4[1];
    const float4 u0 = U4[0], u1 = U4[1];
    const float part = w0.x * u0.x + w0.y * u0.y + w0.z * u0.z + w0.w * u0.w
                     + w1.x * u1.x + w1.y * u1.y + w1.z * u1.z + w1.w * u1.w;
    __shared__ float pb[256];
    pb[t] = part;
    __syncthreads();
    if (t < 64) {
        const float tot = pb[t] + pb[t + 64] + pb[t + 128] + pb[t + 192];
        __hip_atomic_fetch_add(&acc[b * 64 + t], tot,
                               __ATOMIC_RELAXED, __HIP_MEMORY_SCOPE_AGENT);
    }

    // ---- Phase C: completion counter (wave-0 program order + vmcnt only) ----
    __shared__ int lastflag;
    if (t == 0) {
        asm volatile("s_waitcnt vmcnt(0)" ::: "memory");  // acc atomics ack'd
        const int old = __hip_atomic_fetch_add(&cnt[b], 1,
                                               __ATOMIC_RELAXED, __HIP_MEMORY_SCOPE_AGENT);
        lastflag = (old == 31);
    }
    __syncthreads();
    if (lastflag) {
        __shared__ float vsh[64];
        if (t < 64) {
            const float sv = __hip_atomic_load(&acc[b * 64 + t],
                                               __ATOMIC_RELAXED,
                                               __HIP_MEMORY_SCOPE_AGENT);
            const float s1 = sv * (1.0f / 64.0f);
            float sq = s1 * s1;
#pragma unroll
            for (int off = 32; off >= 1; off >>= 1) sq += __shfl_xor(sq, off, 64);
            const float coeff = sqrtf(sq) / (1.0f + sq);  // n^2/(1+n^2)/n
            vsh[t] = s1 * coeff;
        }
        __syncthreads();
        float* ob = out + (size_t)b * 4096;
        const float val = vsh[t & 63];
#pragma unroll
        for (int qq = 0; qq < 16; ++qq) ob[t + 256 * qq] = val;
    }
}

extern "C" void kernel_launch(void* const* d_in, const int* in_sizes, int n_in,
                              void* d_out, int out_size, void* d_ws, size_t ws_size,
                              hipStream_t stream) {
    const float* x = (const float*)d_in[0];   // [64, 1024, 16, 16] fp32
    const float* W = (const float*)d_in[1];   // [32, 64, 32] fp32
    float* out = (float*)d_out;               // [64, 64, 64] fp32
    float* acc = (float*)d_ws;                // [64*64] fp32
    int*   cnt = (int*)((char*)d_ws + 64 * 64 * sizeof(float));  // [64]

    hipMemsetAsync(d_ws, 0, 64 * 64 * sizeof(float) + 64 * sizeof(int), stream);
    k_caplayer<<<2048, 256, 0, stream>>>(x, W, out, acc, cnt);
}